// Round 14
// baseline (168.327 us; speedup 1.0000x reference)
//
#include <hip/hip_runtime.h>
#include <hip/hip_bf16.h>

// ---------------------------------------------------------------------------
// DeepCut fused pipeline. B=4, T=4096 (64x64), D=384, K=8, CH=64, NL=4.
// Graph = 5x5 box stencil, separable. gemm0 + edge-conv bf16 MFMA.
// ecconv: 2 output rows/block (128 blocks) -> A-halo 2x (was 3x), W staging
// halved per row; pitch-36-short LDS rows (stride 18 dwords = conflict-free
// 16-lane frag reads); union LDS 40KB -> 4 blocks/CU. gemm0 B-frags from
// L2-resident global. NO cooperative grid.sync (R8: ~50us/sync).
// Accumulator map (512 floats, zeroed in prep):
//  [0..15] cut num  [16..31] cut den  [32..63] fs partials
//  [64..127] ec GN stats  [128..383] SS  [384..391] sm loss
// ---------------------------------------------------------------------------

#define B_ 4
#define T_ 4096
#define D_ 384

typedef __attribute__((ext_vector_type(8))) short short8b;
typedef __attribute__((ext_vector_type(4))) float f32x4;

__device__ __forceinline__ float wred(float v) {
#pragma unroll
  for (int off = 32; off > 0; off >>= 1) v += __shfl_xor(v, off);
  return v;
}

__device__ __forceinline__ void wred2(float& a, float& b) {
#pragma unroll
  for (int off = 32; off > 0; off >>= 1) {
    a += __shfl_xor(a, off);
    b += __shfl_xor(b, off);
  }
}

__device__ __forceinline__ short bf16rne(float f) {
  unsigned u = __float_as_uint(f);
  unsigned r = (u + 0x7FFFu + ((u >> 16) & 1u)) >> 16;
  return (short)r;
}

__device__ __forceinline__ float bf2f(short s) {
  return __uint_as_float(((unsigned)(unsigned short)s) << 16);
}

__device__ __forceinline__ float uval(int i) {
  int c = (i < 2 ? i : 2) + ((63 - i) < 2 ? (63 - i) : 2) + 1;
  return rsqrtf((float)c);
}

struct PGcn {
  const float *feat, *ecw1, *w0, *resw, *resb, *resg, *reslb;
  const float *gw, *gb0, *gb, *lng, *lnb;
  const float *w1, *b1, *mlng, *mlnb, *w2, *b2;
  short *fb, *wq, *wb;
  float *accg, *xwA, *xwB, *xbuf, *resbuf, *S, *Sp;
};

struct PLoss {
  const float *S, *Sp;
  const float *smw1, *smb1, *smg1, *smbb1, *smw2, *smb2, *smg2, *smbb2;
  const short *fb, *wq;
  const float *ecb1;
  float *eraw, *accg;
  const float *gng, *gnb, *ecw2, *ecb2;
  float *ew, *outp;
};

// ========================= stage device functions ==========================

// prep: feat->bf16 (blk<3072) | wq transpose (3072..3503) | wb (3504..)
__device__ __forceinline__ void prep_stage(int blk, int tid,
    const float* feat, const float* ecw1, const float* w0, const float* resw,
    short* fb, short* wq, short* wb, float* accg) {
  if (blk == 0) {
    accg[tid] = 0.f;
    accg[tid + 256] = 0.f;
  }
  if (blk < 3072) {
    int t = blk * 256 + tid;
    const float4* s = (const float4*)feat + (size_t)t * 2;
    float4 a = s[0], b = s[1];
    short8b v;
    v[0] = bf16rne(a.x); v[1] = bf16rne(a.y); v[2] = bf16rne(a.z); v[3] = bf16rne(a.w);
    v[4] = bf16rne(b.x); v[5] = bf16rne(b.y); v[6] = bf16rne(b.z); v[7] = bf16rne(b.w);
    *(short8b*)(fb + (size_t)t * 8) = v;
  } else if (blk < 3504) {
    int idx = (blk - 3072) * 256 + tid;  // < 110592
    int q = idx % 9;
    int rest = idx / 9;
    int d = rest % 384;
    int o = rest / 384;
    wq[((size_t)(q * 32 + o)) * 384 + d] = bf16rne(ecw1[idx]);
  } else {
    int u = (blk - 3504) * 256 + tid;  // < 6144
    int l = u & 63, f = (u >> 6) & 7, s = u >> 9;
    int c = f * 16 + (l & 15);
    int k0 = s * 32 + ((l >> 4) << 3);
    const float* src = (c < 64) ? (w0 + c) : (resw + (c - 64));
    short8b v;
#pragma unroll
    for (int j = 0; j < 8; ++j) v[j] = bf16rne(src[(size_t)(k0 + j) * 64]);
    *(short8b*)(wb + (size_t)u * 8) = v;
  }
}

// gemm0: 32 rows/block x 128 cols (w0|resw), K=384. A (bf16 fb) staged in
// LDS; B-frags read directly from global wb (L2-hot, coalesced 1KB loads).
__device__ __forceinline__ void gemm0_stage(char* smem, int blk, int tid,
    const short* fb, const short* wb, const float* w0, const float* resw,
    const float* resb, const float* resg, const float* reslb,
    float* xw, float* res) {
  short8b* Ab8 = (short8b*)smem;  // 1536 frags = 24576 B
  int row0 = blk * 32;
#pragma unroll
  for (int it = 0; it < 6; ++it) {
    int u = it * 256 + tid;
    int l = u & 63, s = (u >> 6) % 12, set = u / 768;
    int row = row0 + set * 16 + (l & 15);
    int k = s * 32 + ((l >> 4) << 3);
    Ab8[(set * 12 + s) * 64 + l] = *(const short8b*)(fb + (size_t)row * 384 + k);
  }
  __syncthreads();
  int wid = tid >> 6, lane = tid & 63;
  int rowset = wid & 1, colhalf = wid >> 1;
  const short8b* wb8 = (const short8b*)wb;
  f32x4 acc[4];
#pragma unroll
  for (int f = 0; f < 4; ++f) acc[f] = (f32x4){0.f, 0.f, 0.f, 0.f};
#pragma unroll
  for (int s = 0; s < 12; ++s) {
    short8b av = Ab8[(rowset * 12 + s) * 64 + lane];
#pragma unroll
    for (int f = 0; f < 4; ++f) {
      short8b bv = wb8[((size_t)(s * 8 + colhalf * 4 + f)) * 64 + lane];
      acc[f] = __builtin_amdgcn_mfma_f32_16x16x32_bf16(av, bv, acc[f], 0, 0, 0);
    }
  }
  int g = lane >> 4, ln = lane & 15;
  if (colhalf == 0) {
    float pw1[4], pw2[4];
#pragma unroll
    for (int f = 0; f < 4; ++f) {
      int c = f * 16 + ln;
      pw1[f] = w0[384 * 64 + c];
      pw2[f] = w0[385 * 64 + c];
    }
#pragma unroll
    for (int r = 0; r < 4; ++r) {
      int grow = row0 + rowset * 16 + g * 4 + r;
      int t = grow & (T_ - 1);
      float px = (float)(t & 63) * (1.f / 63.f);
      float py = (float)(t >> 6) * (1.f / 63.f);
#pragma unroll
      for (int f = 0; f < 4; ++f)
        xw[(size_t)grow * 64 + f * 16 + ln] = acc[f][r] + px * pw1[f] + py * pw2[f];
    }
  } else {
    float rw1[4], rw2[4], rb[4], rgam[4], rbet[4];
#pragma unroll
    for (int f = 0; f < 4; ++f) {
      int c = f * 16 + ln;
      rw1[f] = resw[384 * 64 + c];
      rw2[f] = resw[385 * 64 + c];
      rb[f] = resb[c]; rgam[f] = resg[c]; rbet[f] = reslb[c];
    }
#pragma unroll
    for (int r = 0; r < 4; ++r) {
      int grow = row0 + rowset * 16 + g * 4 + r;
      int t = grow & (T_ - 1);
      float px = (float)(t & 63) * (1.f / 63.f);
      float py = (float)(t >> 6) * (1.f / 63.f);
      float rv[4];
      float s1 = 0.f, s2 = 0.f;
#pragma unroll
      for (int f = 0; f < 4; ++f) {
        float v = acc[f][r] + px * rw1[f] + py * rw2[f] + rb[f];
        rv[f] = v;
        s1 += v;
        s2 = fmaf(v, v, s2);
      }
#pragma unroll
      for (int off = 1; off < 16; off <<= 1) {
        s1 += __shfl_xor(s1, off);
        s2 += __shfl_xor(s2, off);
      }
      float mean = s1 * (1.f / 64.f);
      float var = s2 * (1.f / 64.f) - mean * mean;
      float inv = rsqrtf(var + 1e-5f);
#pragma unroll
      for (int f = 0; f < 4; ++f)
        res[(size_t)grow * 64 + f * 16 + ln] =
            (rv[f] - mean) * inv * rgam[f] + rbet[f];
    }
  }
}

// fused layer: separable stencil + LN + ELU + residual, then X@W.
// 16 rows/block (grid 1024); thread = (c=tid&63, jg=tid>>6), jg owns 4 rows.
__device__ __forceinline__ void layer_stage(char* smem, int blk, int tid,
    const float* xw_in, const float* W, const float* bias, const float* lng,
    const float* lnb, const float* resid, float* xout, float* xw_out) {
  float* sx = (float*)smem;            // 16*64 = 4KB
  float* sW = (float*)(smem + 4096);   // 64*64 = 16KB
  int t0 = blk * 16;
  int b = t0 >> 12, i = (t0 >> 6) & 63;
  const float4* w4 = (const float4*)W;
  float4* sW4 = (float4*)sW;
#pragma unroll
  for (int l = 0; l < 4; ++l) sW4[tid + l * 256] = w4[tid + l * 256];
  int c = tid & 63, jg = tid >> 6;
  int jb = (t0 & 63) + jg * 4;
  float ui = uval(i);
  float acc[4];
#pragma unroll
  for (int m = 0; m < 4; ++m) acc[m] = 0.f;
  float uw[8];
#pragma unroll
  for (int d = 0; d < 8; ++d) {
    int jj = jb - 2 + d;
    uw[d] = (jj >= 0 && jj < 64) ? uval(jj) : 0.f;
  }
#pragma unroll
  for (int di = -2; di <= 2; ++di) {
    int ii = i + di;
    if (ii < 0 || ii > 63) continue;
    float wi = uval(ii);
    const float* src = xw_in + ((size_t)((b << 12) + (ii << 6))) * 64 + c;
    float v[8];
#pragma unroll
    for (int d = 0; d < 8; ++d) {
      int jj = jb - 2 + d;
      v[d] = (jj >= 0 && jj < 64) ? src[jj * 64] : 0.f;
    }
#pragma unroll
    for (int m = 0; m < 4; ++m) {
      float t = v[m] * uw[m] + v[m + 1] * uw[m + 1] + v[m + 2] * uw[m + 2] +
                v[m + 3] * uw[m + 3] + v[m + 4] * uw[m + 4];
      acc[m] = fmaf(wi, t, acc[m]);
    }
  }
  float bc = bias[c], gam = lng[c], bet = lnb[c];
#pragma unroll
  for (int m = 0; m < 4; ++m) {
    int lrow = jg * 4 + m;
    float h = ui * uval(jb + m) * acc[m] + bc;
    float s1 = h, s2 = h * h;
    wred2(s1, s2);
    float mean = s1 * (1.f / 64.f);
    float var = s2 * (1.f / 64.f) - mean * mean;
    float n = (h - mean) * rsqrtf(var + 1e-5f) * gam + bet;
    float e = n > 0.f ? n : (expf(n) - 1.f);
    float xv = e + resid[(size_t)(t0 + lrow) * 64 + c];
    xout[(size_t)(t0 + lrow) * 64 + c] = xv;
    sx[lrow * 64 + c] = xv;
  }
  __syncthreads();
  float a[4];
#pragma unroll
  for (int m = 0; m < 4; ++m) a[m] = 0.f;
#pragma unroll
  for (int kq = 0; kq < 16; ++kq) {
    float4 fv[4];
#pragma unroll
    for (int m = 0; m < 4; ++m)
      fv[m] = *(const float4*)&sx[(jg * 4 + m) * 64 + kq * 4];
#pragma unroll
    for (int dk = 0; dk < 4; ++dk) {
      float wv = sW[(kq * 4 + dk) * 64 + c];
#pragma unroll
      for (int m = 0; m < 4; ++m)
        a[m] = fmaf(((const float*)&fv[m])[dk], wv, a[m]);
    }
  }
#pragma unroll
  for (int m = 0; m < 4; ++m)
    xw_out[(size_t)(t0 + jg * 4 + m) * 64 + c] = a[m];
}

// fused final stencil + MLP head (32 rows/block, grid 512)
__device__ __forceinline__ void st4mlp_stage(char* smem, int blk, int tid,
    const float* xw_in, const float* bias, const float* lng, const float* lnb,
    const float* resid, const float* w1, const float* b1, const float* mlng,
    const float* mlnb, const float* w2, const float* b2, float* S, float* Sp) {
  float* sx = (float*)smem;
  float* sW = (float*)(smem + 8192);
  float* sh = (float*)(smem + 24576);
  int t0 = blk * 32;
  int b = t0 >> 12, i = (t0 >> 6) & 63;
  const float4* w4 = (const float4*)w1;
  float4* sW4 = (float4*)sW;
#pragma unroll
  for (int l = 0; l < 4; ++l) sW4[tid + l * 256] = w4[tid + l * 256];
  int c = tid & 63, jg = tid >> 6;
  int jb = (t0 & 63) + jg * 8;
  float ui = uval(i);
  float acc[8];
#pragma unroll
  for (int m = 0; m < 8; ++m) acc[m] = 0.f;
  float uw[12];
#pragma unroll
  for (int d = 0; d < 12; ++d) {
    int jj = jb - 2 + d;
    uw[d] = (jj >= 0 && jj < 64) ? uval(jj) : 0.f;
  }
#pragma unroll
  for (int di = -2; di <= 2; ++di) {
    int ii = i + di;
    if (ii < 0 || ii > 63) continue;
    float wi = uval(ii);
    const float* src = xw_in + ((size_t)((b << 12) + (ii << 6))) * 64 + c;
    float v[12];
#pragma unroll
    for (int d = 0; d < 12; ++d) {
      int jj = jb - 2 + d;
      v[d] = (jj >= 0 && jj < 64) ? src[jj * 64] : 0.f;
    }
#pragma unroll
    for (int m = 0; m < 8; ++m) {
      float t = v[m] * uw[m] + v[m + 1] * uw[m + 1] + v[m + 2] * uw[m + 2] +
                v[m + 3] * uw[m + 3] + v[m + 4] * uw[m + 4];
      acc[m] = fmaf(wi, t, acc[m]);
    }
  }
  float bc = bias[c], gam = lng[c], bet = lnb[c];
#pragma unroll
  for (int m = 0; m < 8; ++m) {
    int lrow = jg * 8 + m;
    float h = ui * uval(jb + m) * acc[m] + bc;
    float s1 = h, s2 = h * h;
    wred2(s1, s2);
    float mean = s1 * (1.f / 64.f);
    float var = s2 * (1.f / 64.f) - mean * mean;
    float n = (h - mean) * rsqrtf(var + 1e-5f) * gam + bet;
    float e = n > 0.f ? n : (expf(n) - 1.f);
    sx[lrow * 64 + c] = e + resid[(size_t)(t0 + lrow) * 64 + c];
  }
  __syncthreads();
  float a[8];
#pragma unroll
  for (int m = 0; m < 8; ++m) a[m] = 0.f;
#pragma unroll
  for (int kq = 0; kq < 16; ++kq) {
    float4 fv[8];
#pragma unroll
    for (int m = 0; m < 8; ++m)
      fv[m] = *(const float4*)&sx[(jg * 8 + m) * 64 + kq * 4];
#pragma unroll
    for (int dk = 0; dk < 4; ++dk) {
      float wv = sW[(kq * 4 + dk) * 64 + c];
#pragma unroll
      for (int m = 0; m < 8; ++m)
        a[m] = fmaf(((const float*)&fv[m])[dk], wv, a[m]);
    }
  }
  float mb = b1[c], mgam = mlng[c], mbet = mlnb[c];
#pragma unroll
  for (int m = 0; m < 8; ++m) {
    float h = a[m] + mb;
    float s1 = h, s2 = h * h;
    wred2(s1, s2);
    float mean = s1 * (1.f / 64.f);
    float var = s2 * (1.f / 64.f) - mean * mean;
    float n = (h - mean) * rsqrtf(var + 1e-5f) * mgam + mbet;
    sh[(jg * 8 + m) * 64 + c] = n > 0.f ? n : (expf(n) - 1.f);
  }
  __syncthreads();
  int k = tid & 7, j = tid >> 3;
  float lg = b2[k];
#pragma unroll 8
  for (int u = 0; u < 64; ++u) {
    int cc = (u + j * 8) & 63;
    lg = fmaf(sh[j * 64 + cc], w2[cc * 8 + k], lg);
  }
  float mx = lg;
  mx = fmaxf(mx, __shfl_xor(mx, 1));
  mx = fmaxf(mx, __shfl_xor(mx, 2));
  mx = fmaxf(mx, __shfl_xor(mx, 4));
  float ex = expf(lg - mx);
  float sum = ex;
  sum += __shfl_xor(sum, 1);
  sum += __shfl_xor(sum, 2);
  sum += __shfl_xor(sum, 4);
  float val = ex / sum;
  int grow = t0 + j;
  int t = grow & (T_ - 1);
  S[(size_t)grow * 8 + k] = val;
  Sp[((size_t)((b << 3) + k) << 12) + t] = val;
}

// normalized cut (+ SS for blk<32)
__device__ __forceinline__ void cut_stage(char* smem, int blk, int tid,
    const float* S, float* accg) {
  {
    int k = tid & 7;
    int tl = tid >> 3;
    int gid = blk * 32 + tl;
    int b = gid >> 12, t = gid & (T_ - 1);
    int i = t >> 6, j = t & 63;
    float ui = uval(i), uj = uval(j);
    float as = 0.f, sui = 0.f, suj = 0.f;
#pragma unroll
    for (int di = -2; di <= 2; ++di) {
      int ii = i + di;
      if (ii < 0 || ii > 63) continue;
      float wi = uval(ii);
      sui += wi;
#pragma unroll
      for (int dj = -2; dj <= 2; ++dj) {
        int jj = j + dj;
        if (jj < 0 || jj > 63) continue;
        as = fmaf(wi * uval(jj),
                  S[((size_t)((b << 12) + (ii << 6) + jj)) * 8 + k], as);
      }
    }
#pragma unroll
    for (int dj = -2; dj <= 2; ++dj) {
      int jj = j + dj;
      if (jj >= 0 && jj <= 63) suj += uval(jj);
    }
    as *= ui * uj;
    float sv = S[(size_t)gid * 8 + k];
    float degA = ui * uj * sui * suj;
    float numv = sv * as, denv = sv * sv * degA;
    wred2(numv, denv);
    float* lds = (float*)smem;
    int wid = tid >> 6, lane = tid & 63;
    if (lane == 0) { lds[wid * 2] = numv; lds[wid * 2 + 1] = denv; }
    __syncthreads();
    if (tid == 0) {
      int slot = b * 4 + (blk & 3);
      atomicAdd(&accg[slot], lds[0] + lds[2] + lds[4] + lds[6]);
      atomicAdd(&accg[16 + slot], lds[1] + lds[3] + lds[5] + lds[7]);
    }
  }
  if (blk < 32) {
    __syncthreads();
    int b = blk >> 3, chunk = blk & 7;
    int wid = tid >> 6, lane = tid & 63;
    int kk = lane >> 3, ll = lane & 7;
    int t0 = chunk * 512 + wid * 128;
    float a = 0.f;
    const float* Sb = S + ((size_t)b << 12) * 8;
    for (int it = 0; it < 128; ++it) {
      const float* sr = Sb + (size_t)(t0 + it) * 8;
      a = fmaf(sr[kk], sr[ll], a);
    }
    float* lds2 = (float*)smem;
    lds2[tid] = a;
    __syncthreads();
    if (tid < 64) {
      float s = lds2[tid] + lds2[tid + 64] + lds2[tid + 128] + lds2[tid + 192];
      atomicAdd(&accg[128 + b * 64 + tid], s);
    }
  }
}

// spatial smoothness per (b,k) plane
__device__ __forceinline__ void sm_stage(char* smem, int bk, int tid,
    const float* Sp, const float* w1, const float* b1, const float* g1,
    const float* bb1, const float* w2, const float* b2, const float* g2,
    const float* bb2, float* accg) {
  float* p0 = (float*)smem;
  float* p1 = p0 + 4096;
  float* red = p1 + 4096;
  int b = bk >> 3, k = bk & 7;
  const float4* src = (const float4*)(Sp + (size_t)bk * 4096);
  float4* d0 = (float4*)p0;
  for (int i2 = tid; i2 < 1024; i2 += 256) d0[i2] = src[i2];
  float W1[9], W2[9];
#pragma unroll
  for (int q = 0; q < 9; ++q) { W1[q] = w1[k * 9 + q]; W2[q] = w2[k * 9 + q]; }
  __syncthreads();
  int wid = tid >> 6, lane = tid & 63;
  float y[16];
  float s1 = 0.f, s2 = 0.f;
#pragma unroll
  for (int v = 0; v < 16; ++v) {
    int p = v * 256 + tid;
    int i2 = p >> 6, j2 = p & 63;
    float a = b1[k];
#pragma unroll
    for (int dy = 0; dy < 3; ++dy) {
      int ii = i2 + dy - 1;
      if (ii < 0 || ii > 63) continue;
#pragma unroll
      for (int dx = 0; dx < 3; ++dx) {
        int jj = j2 + dx - 1;
        if (jj < 0 || jj > 63) continue;
        a = fmaf(W1[dy * 3 + dx], p0[(ii << 6) + jj], a);
      }
    }
    y[v] = a;
    s1 += a;
    s2 = fmaf(a, a, s2);
  }
  wred2(s1, s2);
  if (lane == 0) { red[wid * 2] = s1; red[wid * 2 + 1] = s2; }
  __syncthreads();
  float mean = (red[0] + red[2] + red[4] + red[6]) * (1.f / 4096.f);
  float var = (red[1] + red[3] + red[5] + red[7]) * (1.f / 4096.f) - mean * mean;
  float inv = rsqrtf(var + 1e-5f) * g1[k];
  float sh = bb1[k];
  __syncthreads();
#pragma unroll
  for (int v = 0; v < 16; ++v) {
    int p = v * 256 + tid;
    p1[p] = fmaxf((y[v] - mean) * inv + sh, 0.f);
  }
  __syncthreads();
  s1 = 0.f; s2 = 0.f;
#pragma unroll
  for (int v = 0; v < 16; ++v) {
    int p = v * 256 + tid;
    int i2 = p >> 6, j2 = p & 63;
    float a = b2[k];
#pragma unroll
    for (int dy = 0; dy < 3; ++dy) {
      int ii = i2 + dy - 1;
      if (ii < 0 || ii > 63) continue;
#pragma unroll
      for (int dx = 0; dx < 3; ++dx) {
        int jj = j2 + dx - 1;
        if (jj < 0 || jj > 63) continue;
        a = fmaf(W2[dy * 3 + dx], p1[(ii << 6) + jj], a);
      }
    }
    y[v] = a;
    s1 += a;
    s2 = fmaf(a, a, s2);
  }
  wred2(s1, s2);
  if (lane == 0) { red[wid * 2] = s1; red[wid * 2 + 1] = s2; }
  __syncthreads();
  float mean2 = (red[0] + red[2] + red[4] + red[6]) * (1.f / 4096.f);
  float var2 = (red[1] + red[3] + red[5] + red[7]) * (1.f / 4096.f) - mean2 * mean2;
  float inv2 = rsqrtf(var2 + 1e-5f) * g2[k];
  float sh2 = bb2[k];
  float sd = 0.f;
#pragma unroll
  for (int v = 0; v < 16; ++v) {
    int p = v * 256 + tid;
    float sm = (y[v] - mean2) * inv2 + sh2;
    float dd = sm - p0[p];
    sd = fmaf(dd, dd, sd);
  }
  sd = wred(sd);
  __syncthreads();
  if (lane == 0) red[wid] = sd;
  __syncthreads();
  if (tid == 0)
    atomicAdd(&accg[384 + b * 2 + (bk & 1)],
              (red[0] + red[1] + red[2] + red[3]) * (1.f / 32768.f));
}

// edge conv via bf16 MFMA; 2 output rows per block. A: 4 rows x 67 slots,
// pitch 36 shorts (18-dword stride -> conflict-free 16-lane frag reads);
// W: 9q x 32o, pitch 36. Wave w = (row w>>1, px-half w&1); acc[2 Mtile][2 ch].
__device__ __forceinline__ void ecconv_stage(char* smem, int blk2, int tid,
    const short* fb, const short* wq, const float* ecb1, float* eraw,
    float* accg) {
  short* Abuf = (short*)smem;      // 4*67*36 = 9648 shorts (19296 B)
  short* Wbuf = Abuf + 9648;       // 9*32*36 = 10368 shorts (20736 B)
  float* sW1 = (float*)smem;       // aliases Abuf (used after final barrier)
  float* sW2 = sW1 + 128;
  int b = blk2 >> 5, i0 = (blk2 & 31) * 2;
  int wid = tid >> 6, lane = tid & 63;
  int m = lane & 15, kg = lane >> 4;
  int wr = wid >> 1, wh = wid & 1;
  if (tid < 48) {
    int zkg = tid & 3, sl = (tid >> 2) % 3, r = tid / 12;
    int slot = sl == 0 ? 0 : (sl == 1 ? 65 : 66);
    *(short8b*)&Abuf[(r * 67 + slot) * 36 + zkg * 8] = (short8b)0;
  }
  f32x4 acc00 = {0.f, 0.f, 0.f, 0.f};
  f32x4 acc01 = {0.f, 0.f, 0.f, 0.f};
  f32x4 acc10 = {0.f, 0.f, 0.f, 0.f};
  f32x4 acc11 = {0.f, 0.f, 0.f, 0.f};
  for (int c = 0; c < 12; ++c) {
    __syncthreads();
    // stage A: rows i0-1 .. i0+2 (4 rows) x 64 px x 32 d
#pragma unroll
    for (int s = 0; s < 4; ++s) {
      int cid = tid + (s << 8);
      int akg = cid & 3, px = (cid >> 2) & 63, r = cid >> 8;
      int ii = i0 + r - 1;
      short8b v = (short8b)0;
      if (ii >= 0 && ii < 64)
        v = *(const short8b*)(fb +
              ((size_t)((b << 12) + (ii << 6) + px)) * D_ + c * 32 + akg * 8);
      *(short8b*)&Abuf[(r * 67 + px + 1) * 36 + akg * 8] = v;
    }
    // stage W: 9 q x 32 o x 32 d
    for (int l = tid; l < 1152; l += 256) {
      int wkg = l & 3, oo = (l >> 2) & 31, q = l >> 7;
      short8b wv =
          *(const short8b*)(wq + ((size_t)(q * 32 + oo)) * D_ + c * 32 + wkg * 8);
      *(short8b*)&Wbuf[(q * 32 + oo) * 36 + wkg * 8] = wv;
    }
    __syncthreads();
#pragma unroll
    for (int q = 0; q < 9; ++q) {
      int rloc = wr + q / 3;
      int sbase = (rloc * 67 + wh * 32 + m + (q % 3)) * 36 + kg * 8;
      short8b av0 = *(const short8b*)&Abuf[sbase];
      short8b av1 = *(const short8b*)&Abuf[sbase + 16 * 36];
      short8b bv0 = *(const short8b*)&Wbuf[(q * 32 + m) * 36 + kg * 8];
      short8b bv1 = *(const short8b*)&Wbuf[(q * 32 + 16 + m) * 36 + kg * 8];
      acc00 = __builtin_amdgcn_mfma_f32_16x16x32_bf16(av0, bv0, acc00, 0, 0, 0);
      acc01 = __builtin_amdgcn_mfma_f32_16x16x32_bf16(av0, bv1, acc01, 0, 0, 0);
      acc10 = __builtin_amdgcn_mfma_f32_16x16x32_bf16(av1, bv0, acc10, 0, 0, 0);
      acc11 = __builtin_amdgcn_mfma_f32_16x16x32_bf16(av1, bv1, acc11, 0, 0, 0);
    }
  }
  __syncthreads();  // Abuf dead; sW1/sW2 alias it
  int orow = i0 + wr;
  float bs0 = ecb1[m], bs1 = ecb1[16 + m];
  float s1a = 0.f, s2a = 0.f, s1b = 0.f, s2b = 0.f;
#pragma unroll
  for (int rg = 0; rg < 4; ++rg) {
    int j0 = wh * 32 + kg * 4 + rg;
    int j1 = j0 + 16;
    size_t px0 = ((size_t)((b << 12) + (orow << 6) + j0)) * 32;
    size_t px1 = ((size_t)((b << 12) + (orow << 6) + j1)) * 32;
    float v00 = acc00[rg] + bs0, v01 = acc01[rg] + bs1;
    float v10 = acc10[rg] + bs0, v11 = acc11[rg] + bs1;
    eraw[px0 + m] = v00;
    eraw[px0 + 16 + m] = v01;
    eraw[px1 + m] = v10;
    eraw[px1 + 16 + m] = v11;
    s1a += v00 + v10; s2a = fmaf(v00, v00, fmaf(v10, v10, s2a));
    s1b += v01 + v11; s2b = fmaf(v01, v01, fmaf(v11, v11, s2b));
  }
  s1a += __shfl_xor(s1a, 16); s1a += __shfl_xor(s1a, 32);
  s2a += __shfl_xor(s2a, 16); s2a += __shfl_xor(s2a, 32);
  s1b += __shfl_xor(s1b, 16); s1b += __shfl_xor(s1b, 32);
  s2b += __shfl_xor(s2b, 16); s2b += __shfl_xor(s2b, 32);
  if (lane < 16) {
    sW1[wid * 32 + lane] = s1a; sW2[wid * 32 + lane] = s2a;
    sW1[wid * 32 + lane + 16] = s1b; sW2[wid * 32 + lane + 16] = s2b;
  }
  __syncthreads();
  if (tid < 32) {
    float t1 = sW1[tid] + sW1[32 + tid] + sW1[64 + tid] + sW1[96 + tid];
    float t2 = sW2[tid] + sW2[32 + tid] + sW2[64 + tid] + sW2[96 + tid];
    t1 += __shfl_xor(t1, 1); t1 += __shfl_xor(t1, 2);
    t2 += __shfl_xor(t2, 1); t2 += __shfl_xor(t2, 2);
    if ((tid & 3) == 0) {
      atomicAdd(&accg[64 + b * 16 + (tid >> 2) * 2], t1);
      atomicAdd(&accg[64 + b * 16 + (tid >> 2) * 2 + 1], t2);
    }
  }
}

__device__ __forceinline__ void ecfinal_stage(char* smem, int blk, int tid,
    const float* eraw, const float* accg, const float* gng, const float* gnb,
    const float* w2, const float* b2, float* ew) {
  float* st = (float*)smem;
  int idx = blk * 256 + tid;
  int b = idx >> 12;
  if (tid < 16) st[tid] = accg[64 + b * 16 + tid];
  __syncthreads();
  float a = b2[0];
  const float4* er = (const float4*)(eraw + (size_t)idx * 32);
#pragma unroll
  for (int oq = 0; oq < 8; ++oq) {
    float mean = st[oq * 2] * (1.f / 16384.f);
    float var = st[oq * 2 + 1] * (1.f / 16384.f) - mean * mean;
    float inv = rsqrtf(var + 1e-5f);
    float4 e = er[oq];
    int o = oq * 4;
    float v0 = (e.x - mean) * inv * gng[o + 0] + gnb[o + 0];
    float v1 = (e.y - mean) * inv * gng[o + 1] + gnb[o + 1];
    float v2 = (e.z - mean) * inv * gng[o + 2] + gnb[o + 2];
    float v3 = (e.w - mean) * inv * gng[o + 3] + gnb[o + 3];
    a = fmaf(fmaxf(v0, 0.f), w2[o + 0], a);
    a = fmaf(fmaxf(v1, 0.f), w2[o + 1], a);
    a = fmaf(fmaxf(v2, 0.f), w2[o + 2], a);
    a = fmaf(fmaxf(v3, 0.f), w2[o + 3], a);
  }
  ew[idx] = 1.f / (1.f + expf(-a));
}

// feature-smoothness gradient sums (bf16 fb); scattered atomics
__device__ __forceinline__ void fsloss_stage(char* smem, int blk, int tid,
    const short* fb, const float* ew, float* accg) {
  float sy = 0.f, sx = 0.f;
  const int N = B_ * T_ * 48;
  for (int idx = blk * 256 + tid; idx < N; idx += 512 * 256) {
    int d8 = idx % 48;
    int rt = idx / 48;
    int t = rt & (T_ - 1);
    int i = t >> 6, j = t & 63;
    const short8b* fp = (const short8b*)(fb + (size_t)rt * D_) + d8;
    short8b f0 = *fp;
    if (i < 63) {
      short8b f1 = fp[64 * 48];
      float w = ew[rt + 64];
      float a = 0.f;
#pragma unroll
      for (int u = 0; u < 8; ++u) {
        float d = bf2f(f1[u]) - bf2f(f0[u]);
        a = fmaf(d, d, a);
      }
      sy += w * a;
    }
    if (j < 63) {
      short8b f1 = fp[48];
      float w = ew[rt + 1];
      float a = 0.f;
#pragma unroll
      for (int u = 0; u < 8; ++u) {
        float d = bf2f(f1[u]) - bf2f(f0[u]);
        a = fmaf(d, d, a);
      }
      sx += w * a;
    }
  }
  wred2(sy, sx);
  float* lds = (float*)smem;
  int wid = tid >> 6, lane = tid & 63;
  if (lane == 0) { lds[wid * 2] = sy; lds[wid * 2 + 1] = sx; }
  __syncthreads();
  if (tid == 0) {
    int slot = 32 + (blk & 15) * 2;
    atomicAdd(&accg[slot], lds[0] + lds[2] + lds[4] + lds[6]);
    atomicAdd(&accg[slot + 1], lds[1] + lds[3] + lds[5] + lds[7]);
  }
}

__device__ __forceinline__ void final_stage(const float* accg, float* out) {
  float total = 0.f;
  for (int b = 0; b < 4; ++b) {
    const float* SSb = accg + 128 + b * 64;
    float ssq = 0.f;
    for (int v = 0; v < 64; ++v) ssq += SSb[v] * SSb[v];
    float ssn = sqrtf(ssq);
    float tgt = 1.f / (sqrtf(8.f) + 1e-6f);
    float inv = 1.f / (ssn + 1e-6f);
    float lo = 0.f;
    for (int kk = 0; kk < 8; ++kk)
      for (int ll = 0; ll < 8; ++ll) {
        float dd = SSb[kk * 8 + ll] * inv - (kk == ll ? tgt : 0.f);
        lo += dd * dd;
      }
    lo = sqrtf(lo);
    float num = accg[b * 4] + accg[b * 4 + 1] + accg[b * 4 + 2] + accg[b * 4 + 3];
    float den = accg[16 + b * 4] + accg[16 + b * 4 + 1] + accg[16 + b * 4 + 2] +
                accg[16 + b * 4 + 3];
    float lc = -num / (den + 1e-6f);
    float smv = accg[384 + b * 2] + accg[385 + b * 2];
    total += lc + lo + 0.01f * smv;
  }
  total *= 0.25f;
  float fsy = 0.f, fsx = 0.f;
  for (int s = 0; s < 16; ++s) { fsy += accg[32 + s * 2]; fsx += accg[33 + s * 2]; }
  const float cnt = 4.f * 384.f * 63.f * 64.f;
  float ly = fsy / cnt * (1.f / 384.f);
  float lx = fsx / cnt * (1.f / 384.f);
  out[131072] = total + 0.09f * 0.5f * (ly + lx);
}

// ============================ kernels ======================================

__global__ __launch_bounds__(256) void k_prep(PGcn p) {
  prep_stage(blockIdx.x, threadIdx.x, p.feat, p.ecw1, p.w0, p.resw, p.fb, p.wq,
             p.wb, p.accg);
}

// ecconv (blk<128, XCD-swizzled, 2 rows/block) || gemm0 (blk>=128, 512 blocks)
__global__ __launch_bounds__(256) void k_mix1(PGcn g, PLoss l) {
  __shared__ __align__(16) char smem[40064];
  if (blockIdx.x < 128) {
    int lb = (blockIdx.x & 7) * 16 + (blockIdx.x >> 3);  // XCD-contiguous pairs
    ecconv_stage(smem, lb, threadIdx.x, l.fb, l.wq, l.ecb1, l.eraw, l.accg);
  } else {
    gemm0_stage(smem, blockIdx.x - 128, threadIdx.x, g.fb, g.wb, g.w0, g.resw,
                g.resb, g.resg, g.reslb, g.xwA, g.resbuf);
  }
}

// ecfinal (blk<64) || layer0 (blk>=64, 1024 blocks)
__global__ __launch_bounds__(256) void k_mix2(PGcn g, PLoss l) {
  __shared__ __align__(16) char smem[20480];
  if (blockIdx.x < 64)
    ecfinal_stage(smem, blockIdx.x, threadIdx.x, l.eraw, l.accg, l.gng, l.gnb,
                  l.ecw2, l.ecb2, l.ew);
  else
    layer_stage(smem, blockIdx.x - 64, threadIdx.x, g.xwA, g.gw, g.gb0, g.lng,
                g.lnb, g.resbuf, g.xbuf, g.xwB);
}

// fsloss (blk<512) || layer1 (blk>=512, 1024 blocks)
__global__ __launch_bounds__(256) void k_mix3(PGcn g, PLoss l) {
  __shared__ __align__(16) char smem[20480];
  if (blockIdx.x < 512)
    fsloss_stage(smem, blockIdx.x, threadIdx.x, l.fb, l.ew, l.accg);
  else
    layer_stage(smem, blockIdx.x - 512, threadIdx.x, g.xwB, g.gw + 4096, g.gb,
                g.lng + 64, g.lnb + 64, g.xbuf, g.xbuf, g.xwA);
}

__global__ __launch_bounds__(256) void k_layer2(PGcn p) {
  __shared__ __align__(16) char smem[20480];
  layer_stage(smem, blockIdx.x, threadIdx.x, p.xwA, p.gw + 8192, p.gb + 64,
              p.lng + 128, p.lnb + 128, p.xbuf, p.xbuf, p.xwB);
}

__global__ __launch_bounds__(256) void k_st4mlp(PGcn p) {
  __shared__ __align__(16) char smem[32768];
  st4mlp_stage(smem, blockIdx.x, threadIdx.x, p.xwB, p.gb + 128, p.lng + 192,
               p.lnb + 192, p.xbuf, p.w1, p.b1, p.mlng, p.mlnb, p.w2, p.b2,
               p.S, p.Sp);
}

// cut (blk<512) || sm (blk>=512, 32 blocks)
__global__ __launch_bounds__(256) void k_cutsm(PLoss p) {
  __shared__ __align__(16) char smem[32832];
  if (blockIdx.x < 512)
    cut_stage(smem, blockIdx.x, threadIdx.x, p.S, p.accg);
  else
    sm_stage(smem, blockIdx.x - 512, threadIdx.x, p.Sp, p.smw1, p.smb1, p.smg1,
             p.smbb1, p.smw2, p.smb2, p.smg2, p.smbb2, p.accg);
}

__global__ void k_final(PLoss p) {
  if (threadIdx.x == 0 && blockIdx.x == 0) final_stage(p.accg, p.outp);
}

// ================================ host =====================================

extern "C" void kernel_launch(void* const* d_in, const int* in_sizes, int n_in,
                              void* d_out, int out_size, void* d_ws, size_t ws_size,
                              hipStream_t stream) {
  const float* feat = (const float*)d_in[0];
  const float* gcn_w0 = (const float*)d_in[1];
  const float* gcn_b0 = (const float*)d_in[2];
  const float* gcn_w = (const float*)d_in[3];
  const float* gcn_b = (const float*)d_in[4];
  const float* ln_g = (const float*)d_in[5];
  const float* ln_b = (const float*)d_in[6];
  const float* res_w = (const float*)d_in[7];
  const float* res_b = (const float*)d_in[8];
  const float* res_ln_g = (const float*)d_in[9];
  const float* res_ln_b = (const float*)d_in[10];
  const float* mlp_w1 = (const float*)d_in[11];
  const float* mlp_b1 = (const float*)d_in[12];
  const float* mlp_ln_g = (const float*)d_in[13];
  const float* mlp_ln_b = (const float*)d_in[14];
  const float* mlp_w2 = (const float*)d_in[15];
  const float* mlp_b2 = (const float*)d_in[16];
  const float* sm_w1 = (const float*)d_in[17];
  const float* sm_b1 = (const float*)d_in[18];
  const float* sm_g1 = (const float*)d_in[19];
  const float* sm_bb1 = (const float*)d_in[20];
  const float* sm_w2 = (const float*)d_in[21];
  const float* sm_b2 = (const float*)d_in[22];
  const float* sm_g2 = (const float*)d_in[23];
  const float* sm_bb2 = (const float*)d_in[24];
  const float* ec_w1 = (const float*)d_in[25];
  const float* ec_b1 = (const float*)d_in[26];
  const float* ec_gn_g = (const float*)d_in[27];
  const float* ec_gn_b = (const float*)d_in[28];
  const float* ec_w2 = (const float*)d_in[29];
  const float* ec_b2 = (const float*)d_in[30];

  float* out = (float*)d_out;
  float* ws = (float*)d_ws;
  float* acc = ws;                       // 512 floats
  float* xwA = ws + 512;
  float* xwB = xwA + 1048576;
  float* xbuf = xwB + 1048576;
  float* resbuf = xbuf + 1048576;
  float* Sp = resbuf + 1048576;          // B*K*T
  float* eraw = Sp + 131072;             // B*T*32 pixel-major
  float* ew = eraw + 524288;             // B*T
  short* wqb = (short*)(ew + 16384);     // 110592 bf16
  short* wb = wqb + 110592;              // 49152 bf16 frag order
  short* fb = wb + 49152;                // B*T*384 bf16 (prep)
  float* S = out;

  PGcn pg = {feat, ec_w1, gcn_w0, res_w, res_b, res_ln_g, res_ln_b,
             gcn_w, gcn_b0, gcn_b, ln_g, ln_b,
             mlp_w1, mlp_b1, mlp_ln_g, mlp_ln_b, mlp_w2, mlp_b2,
             fb, wqb, wb, acc, xwA, xwB, xbuf, resbuf, S, Sp};
  PLoss pl = {S, Sp, sm_w1, sm_b1, sm_g1, sm_bb1, sm_w2, sm_b2, sm_g2, sm_bb2,
              fb, wqb, ec_b1, eraw, acc, ec_gn_g, ec_gn_b, ec_w2, ec_b2, ew,
              out};

  k_prep<<<3528, 256, 0, stream>>>(pg);
  k_mix1<<<640, 256, 0, stream>>>(pg, pl);    // ecconv(128) || gemm0(512)
  k_mix2<<<1088, 256, 0, stream>>>(pg, pl);   // ecfinal || layer0
  k_mix3<<<1536, 256, 0, stream>>>(pg, pl);   // fsloss || layer1
  k_layer2<<<1024, 256, 0, stream>>>(pg);
  k_st4mlp<<<512, 256, 0, stream>>>(pg);
  k_cutsm<<<544, 256, 0, stream>>>(pl);       // cut || sm
  k_final<<<1, 64, 0, stream>>>(pl);
}

// Round 15
// 124.585 us; speedup vs baseline: 1.3511x; 1.3511x over previous
//
#include <hip/hip_runtime.h>
#include <hip/hip_bf16.h>

// ---------------------------------------------------------------------------
// DeepCut fused pipeline. B=4, T=4096 (64x64), D=384, K=8, CH=64, NL=4.
// Graph = 5x5 box stencil, separable. gemm0 + edge-conv bf16 MFMA.
// 8 discrete launches; independent DAG branches co-scheduled as block-range
// unions (ecconv||gemm0, ecfinal||layer0, fsloss||layer1). NO cooperative
// grid.sync (measured ~50us/sync on 8-XCD MI355X in R8).
// BEST-KNOWN CONFIG (R9 proposal, 124.8us): fb materialized in prep; mix1
// stages A+W (ecconv) and A+B (gemm0) in LDS; 16-row layer blocks.
// Accumulator map (512 floats, zeroed in prep stage):
//  [0..15] cut num  [16..31] cut den  [32..63] fs partials
//  [64..127] ec GN stats  [128..383] SS  [384..391] sm loss
// ---------------------------------------------------------------------------

#define B_ 4
#define T_ 4096
#define D_ 384

typedef __attribute__((ext_vector_type(8))) short short8b;
typedef __attribute__((ext_vector_type(4))) float f32x4;

__device__ __forceinline__ float wred(float v) {
#pragma unroll
  for (int off = 32; off > 0; off >>= 1) v += __shfl_xor(v, off);
  return v;
}

__device__ __forceinline__ void wred2(float& a, float& b) {
#pragma unroll
  for (int off = 32; off > 0; off >>= 1) {
    a += __shfl_xor(a, off);
    b += __shfl_xor(b, off);
  }
}

__device__ __forceinline__ short bf16rne(float f) {
  unsigned u = __float_as_uint(f);
  unsigned r = (u + 0x7FFFu + ((u >> 16) & 1u)) >> 16;
  return (short)r;
}

__device__ __forceinline__ float bf2f(short s) {
  return __uint_as_float(((unsigned)(unsigned short)s) << 16);
}

__device__ __forceinline__ float uval(int i) {
  int c = (i < 2 ? i : 2) + ((63 - i) < 2 ? (63 - i) : 2) + 1;
  return rsqrtf((float)c);
}

struct PGcn {
  const float *feat, *ecw1, *w0, *resw, *resb, *resg, *reslb;
  const float *gw, *gb0, *gb, *lng, *lnb;
  const float *w1, *b1, *mlng, *mlnb, *w2, *b2;
  short *fb, *wq, *wb;
  float *accg, *xwA, *xwB, *xbuf, *resbuf, *S, *Sp;
};

struct PLoss {
  const float *S, *Sp;
  const float *smw1, *smb1, *smg1, *smbb1, *smw2, *smb2, *smg2, *smbb2;
  const short *fb, *wq;
  const float *ecb1;
  float *eraw, *accg;
  const float *gng, *gnb, *ecw2, *ecb2;
  float *ew, *outp;
};

// ========================= stage device functions ==========================

// prep: feat->bf16 (blk<3072) | wq transpose (3072..3503) | wb (3504..)
__device__ __forceinline__ void prep_stage(int blk, int tid,
    const float* feat, const float* ecw1, const float* w0, const float* resw,
    short* fb, short* wq, short* wb, float* accg) {
  if (blk == 0) {
    accg[tid] = 0.f;
    accg[tid + 256] = 0.f;
  }
  if (blk < 3072) {
    int t = blk * 256 + tid;
    const float4* s = (const float4*)feat + (size_t)t * 2;
    float4 a = s[0], b = s[1];
    short8b v;
    v[0] = bf16rne(a.x); v[1] = bf16rne(a.y); v[2] = bf16rne(a.z); v[3] = bf16rne(a.w);
    v[4] = bf16rne(b.x); v[5] = bf16rne(b.y); v[6] = bf16rne(b.z); v[7] = bf16rne(b.w);
    *(short8b*)(fb + (size_t)t * 8) = v;
  } else if (blk < 3504) {
    int idx = (blk - 3072) * 256 + tid;  // < 110592
    int q = idx % 9;
    int rest = idx / 9;
    int d = rest % 384;
    int o = rest / 384;
    wq[((size_t)(q * 32 + o)) * 384 + d] = bf16rne(ecw1[idx]);
  } else {
    int u = (blk - 3504) * 256 + tid;  // < 6144
    int l = u & 63, f = (u >> 6) & 7, s = u >> 9;
    int c = f * 16 + (l & 15);
    int k0 = s * 32 + ((l >> 4) << 3);
    const float* src = (c < 64) ? (w0 + c) : (resw + (c - 64));
    short8b v;
#pragma unroll
    for (int j = 0; j < 8; ++j) v[j] = bf16rne(src[(size_t)(k0 + j) * 64]);
    *(short8b*)(wb + (size_t)u * 8) = v;
  }
}

// gemm0: 32 rows/block x 128 cols (w0|resw), K=384 in 3 chunks of 128.
// wave w: rowset=w&1 (16 rows), colhalf=w>>1 (64 cols).
__device__ __forceinline__ void gemm0_stage(char* smem, int blk, int tid,
    const short* fb, const short* wb, const float* w0, const float* resw,
    const float* resb, const float* resg, const float* reslb,
    float* xw, float* res) {
  short8b* Ab8 = (short8b*)smem;            // 24576 B
  short8b* Bb8 = (short8b*)(smem + 24576);  // 32768 B
  int row0 = blk * 32;
#pragma unroll
  for (int it = 0; it < 6; ++it) {
    int u = it * 256 + tid;
    int l = u & 63, s = (u >> 6) % 12, set = u / 768;
    int row = row0 + set * 16 + (l & 15);
    int k = s * 32 + ((l >> 4) << 3);
    Ab8[(set * 12 + s) * 64 + l] = *(const short8b*)(fb + (size_t)row * 384 + k);
  }
  int wid = tid >> 6, lane = tid & 63;
  int rowset = wid & 1, colhalf = wid >> 1;
  const short8b* wb8 = (const short8b*)wb;
  f32x4 acc[4];
#pragma unroll
  for (int f = 0; f < 4; ++f) acc[f] = (f32x4){0.f, 0.f, 0.f, 0.f};
  for (int c = 0; c < 3; ++c) {
    __syncthreads();
#pragma unroll
    for (int it = 0; it < 8; ++it) {
      int u = it * 256 + tid;
      Bb8[u] = wb8[c * 2048 + u];
    }
    __syncthreads();
#pragma unroll
    for (int s = 0; s < 4; ++s) {
      short8b av = Ab8[(rowset * 12 + c * 4 + s) * 64 + lane];
#pragma unroll
      for (int f = 0; f < 4; ++f) {
        short8b bv = Bb8[(s * 8 + colhalf * 4 + f) * 64 + lane];
        acc[f] = __builtin_amdgcn_mfma_f32_16x16x32_bf16(av, bv, acc[f], 0, 0, 0);
      }
    }
  }
  int g = lane >> 4, ln = lane & 15;
  if (colhalf == 0) {
    float pw1[4], pw2[4];
#pragma unroll
    for (int f = 0; f < 4; ++f) {
      int c = f * 16 + ln;
      pw1[f] = w0[384 * 64 + c];
      pw2[f] = w0[385 * 64 + c];
    }
#pragma unroll
    for (int r = 0; r < 4; ++r) {
      int grow = row0 + rowset * 16 + g * 4 + r;
      int t = grow & (T_ - 1);
      float px = (float)(t & 63) * (1.f / 63.f);
      float py = (float)(t >> 6) * (1.f / 63.f);
#pragma unroll
      for (int f = 0; f < 4; ++f)
        xw[(size_t)grow * 64 + f * 16 + ln] = acc[f][r] + px * pw1[f] + py * pw2[f];
    }
  } else {
    float rw1[4], rw2[4], rb[4], rgam[4], rbet[4];
#pragma unroll
    for (int f = 0; f < 4; ++f) {
      int c = f * 16 + ln;
      rw1[f] = resw[384 * 64 + c];
      rw2[f] = resw[385 * 64 + c];
      rb[f] = resb[c]; rgam[f] = resg[c]; rbet[f] = reslb[c];
    }
#pragma unroll
    for (int r = 0; r < 4; ++r) {
      int grow = row0 + rowset * 16 + g * 4 + r;
      int t = grow & (T_ - 1);
      float px = (float)(t & 63) * (1.f / 63.f);
      float py = (float)(t >> 6) * (1.f / 63.f);
      float rv[4];
      float s1 = 0.f, s2 = 0.f;
#pragma unroll
      for (int f = 0; f < 4; ++f) {
        float v = acc[f][r] + px * rw1[f] + py * rw2[f] + rb[f];
        rv[f] = v;
        s1 += v;
        s2 = fmaf(v, v, s2);
      }
#pragma unroll
      for (int off = 1; off < 16; off <<= 1) {
        s1 += __shfl_xor(s1, off);
        s2 += __shfl_xor(s2, off);
      }
      float mean = s1 * (1.f / 64.f);
      float var = s2 * (1.f / 64.f) - mean * mean;
      float inv = rsqrtf(var + 1e-5f);
#pragma unroll
      for (int f = 0; f < 4; ++f)
        res[(size_t)grow * 64 + f * 16 + ln] =
            (rv[f] - mean) * inv * rgam[f] + rbet[f];
    }
  }
}

// fused layer: separable stencil + LN + ELU + residual, then X@W.
// 16 rows/block (grid 1024); thread = (c=tid&63, jg=tid>>6), jg owns 4 rows.
__device__ __forceinline__ void layer_stage(char* smem, int blk, int tid,
    const float* xw_in, const float* W, const float* bias, const float* lng,
    const float* lnb, const float* resid, float* xout, float* xw_out) {
  float* sx = (float*)smem;            // 16*64 = 4KB
  float* sW = (float*)(smem + 4096);   // 64*64 = 16KB
  int t0 = blk * 16;
  int b = t0 >> 12, i = (t0 >> 6) & 63;
  const float4* w4 = (const float4*)W;
  float4* sW4 = (float4*)sW;
#pragma unroll
  for (int l = 0; l < 4; ++l) sW4[tid + l * 256] = w4[tid + l * 256];
  int c = tid & 63, jg = tid >> 6;
  int jb = (t0 & 63) + jg * 4;
  float ui = uval(i);
  float acc[4];
#pragma unroll
  for (int m = 0; m < 4; ++m) acc[m] = 0.f;
  float uw[8];
#pragma unroll
  for (int d = 0; d < 8; ++d) {
    int jj = jb - 2 + d;
    uw[d] = (jj >= 0 && jj < 64) ? uval(jj) : 0.f;
  }
#pragma unroll
  for (int di = -2; di <= 2; ++di) {
    int ii = i + di;
    if (ii < 0 || ii > 63) continue;
    float wi = uval(ii);
    const float* src = xw_in + ((size_t)((b << 12) + (ii << 6))) * 64 + c;
    float v[8];
#pragma unroll
    for (int d = 0; d < 8; ++d) {
      int jj = jb - 2 + d;
      v[d] = (jj >= 0 && jj < 64) ? src[jj * 64] : 0.f;
    }
#pragma unroll
    for (int m = 0; m < 4; ++m) {
      float t = v[m] * uw[m] + v[m + 1] * uw[m + 1] + v[m + 2] * uw[m + 2] +
                v[m + 3] * uw[m + 3] + v[m + 4] * uw[m + 4];
      acc[m] = fmaf(wi, t, acc[m]);
    }
  }
  float bc = bias[c], gam = lng[c], bet = lnb[c];
#pragma unroll
  for (int m = 0; m < 4; ++m) {
    int lrow = jg * 4 + m;
    float h = ui * uval(jb + m) * acc[m] + bc;
    float s1 = h, s2 = h * h;
    wred2(s1, s2);
    float mean = s1 * (1.f / 64.f);
    float var = s2 * (1.f / 64.f) - mean * mean;
    float n = (h - mean) * rsqrtf(var + 1e-5f) * gam + bet;
    float e = n > 0.f ? n : (expf(n) - 1.f);
    float xv = e + resid[(size_t)(t0 + lrow) * 64 + c];
    xout[(size_t)(t0 + lrow) * 64 + c] = xv;
    sx[lrow * 64 + c] = xv;
  }
  __syncthreads();
  float a[4];
#pragma unroll
  for (int m = 0; m < 4; ++m) a[m] = 0.f;
#pragma unroll
  for (int kq = 0; kq < 16; ++kq) {
    float4 fv[4];
#pragma unroll
    for (int m = 0; m < 4; ++m)
      fv[m] = *(const float4*)&sx[(jg * 4 + m) * 64 + kq * 4];
#pragma unroll
    for (int dk = 0; dk < 4; ++dk) {
      float wv = sW[(kq * 4 + dk) * 64 + c];
#pragma unroll
      for (int m = 0; m < 4; ++m)
        a[m] = fmaf(((const float*)&fv[m])[dk], wv, a[m]);
    }
  }
#pragma unroll
  for (int m = 0; m < 4; ++m)
    xw_out[(size_t)(t0 + jg * 4 + m) * 64 + c] = a[m];
}

// fused final stencil + MLP head (32 rows/block, grid 512)
__device__ __forceinline__ void st4mlp_stage(char* smem, int blk, int tid,
    const float* xw_in, const float* bias, const float* lng, const float* lnb,
    const float* resid, const float* w1, const float* b1, const float* mlng,
    const float* mlnb, const float* w2, const float* b2, float* S, float* Sp) {
  float* sx = (float*)smem;
  float* sW = (float*)(smem + 8192);
  float* sh = (float*)(smem + 24576);
  int t0 = blk * 32;
  int b = t0 >> 12, i = (t0 >> 6) & 63;
  const float4* w4 = (const float4*)w1;
  float4* sW4 = (float4*)sW;
#pragma unroll
  for (int l = 0; l < 4; ++l) sW4[tid + l * 256] = w4[tid + l * 256];
  int c = tid & 63, jg = tid >> 6;
  int jb = (t0 & 63) + jg * 8;
  float ui = uval(i);
  float acc[8];
#pragma unroll
  for (int m = 0; m < 8; ++m) acc[m] = 0.f;
  float uw[12];
#pragma unroll
  for (int d = 0; d < 12; ++d) {
    int jj = jb - 2 + d;
    uw[d] = (jj >= 0 && jj < 64) ? uval(jj) : 0.f;
  }
#pragma unroll
  for (int di = -2; di <= 2; ++di) {
    int ii = i + di;
    if (ii < 0 || ii > 63) continue;
    float wi = uval(ii);
    const float* src = xw_in + ((size_t)((b << 12) + (ii << 6))) * 64 + c;
    float v[12];
#pragma unroll
    for (int d = 0; d < 12; ++d) {
      int jj = jb - 2 + d;
      v[d] = (jj >= 0 && jj < 64) ? src[jj * 64] : 0.f;
    }
#pragma unroll
    for (int m = 0; m < 8; ++m) {
      float t = v[m] * uw[m] + v[m + 1] * uw[m + 1] + v[m + 2] * uw[m + 2] +
                v[m + 3] * uw[m + 3] + v[m + 4] * uw[m + 4];
      acc[m] = fmaf(wi, t, acc[m]);
    }
  }
  float bc = bias[c], gam = lng[c], bet = lnb[c];
#pragma unroll
  for (int m = 0; m < 8; ++m) {
    int lrow = jg * 8 + m;
    float h = ui * uval(jb + m) * acc[m] + bc;
    float s1 = h, s2 = h * h;
    wred2(s1, s2);
    float mean = s1 * (1.f / 64.f);
    float var = s2 * (1.f / 64.f) - mean * mean;
    float n = (h - mean) * rsqrtf(var + 1e-5f) * gam + bet;
    float e = n > 0.f ? n : (expf(n) - 1.f);
    sx[lrow * 64 + c] = e + resid[(size_t)(t0 + lrow) * 64 + c];
  }
  __syncthreads();
  float a[8];
#pragma unroll
  for (int m = 0; m < 8; ++m) a[m] = 0.f;
#pragma unroll
  for (int kq = 0; kq < 16; ++kq) {
    float4 fv[8];
#pragma unroll
    for (int m = 0; m < 8; ++m)
      fv[m] = *(const float4*)&sx[(jg * 8 + m) * 64 + kq * 4];
#pragma unroll
    for (int dk = 0; dk < 4; ++dk) {
      float wv = sW[(kq * 4 + dk) * 64 + c];
#pragma unroll
      for (int m = 0; m < 8; ++m)
        a[m] = fmaf(((const float*)&fv[m])[dk], wv, a[m]);
    }
  }
  float mb = b1[c], mgam = mlng[c], mbet = mlnb[c];
#pragma unroll
  for (int m = 0; m < 8; ++m) {
    float h = a[m] + mb;
    float s1 = h, s2 = h * h;
    wred2(s1, s2);
    float mean = s1 * (1.f / 64.f);
    float var = s2 * (1.f / 64.f) - mean * mean;
    float n = (h - mean) * rsqrtf(var + 1e-5f) * mgam + mbet;
    sh[(jg * 8 + m) * 64 + c] = n > 0.f ? n : (expf(n) - 1.f);
  }
  __syncthreads();
  int k = tid & 7, j = tid >> 3;
  float lg = b2[k];
#pragma unroll 8
  for (int u = 0; u < 64; ++u) {
    int cc = (u + j * 8) & 63;
    lg = fmaf(sh[j * 64 + cc], w2[cc * 8 + k], lg);
  }
  float mx = lg;
  mx = fmaxf(mx, __shfl_xor(mx, 1));
  mx = fmaxf(mx, __shfl_xor(mx, 2));
  mx = fmaxf(mx, __shfl_xor(mx, 4));
  float ex = expf(lg - mx);
  float sum = ex;
  sum += __shfl_xor(sum, 1);
  sum += __shfl_xor(sum, 2);
  sum += __shfl_xor(sum, 4);
  float val = ex / sum;
  int grow = t0 + j;
  int t = grow & (T_ - 1);
  S[(size_t)grow * 8 + k] = val;
  Sp[((size_t)((b << 3) + k) << 12) + t] = val;
}

// normalized cut (+ SS for blk<32)
__device__ __forceinline__ void cut_stage(char* smem, int blk, int tid,
    const float* S, float* accg) {
  {
    int k = tid & 7;
    int tl = tid >> 3;
    int gid = blk * 32 + tl;
    int b = gid >> 12, t = gid & (T_ - 1);
    int i = t >> 6, j = t & 63;
    float ui = uval(i), uj = uval(j);
    float as = 0.f, sui = 0.f, suj = 0.f;
#pragma unroll
    for (int di = -2; di <= 2; ++di) {
      int ii = i + di;
      if (ii < 0 || ii > 63) continue;
      float wi = uval(ii);
      sui += wi;
#pragma unroll
      for (int dj = -2; dj <= 2; ++dj) {
        int jj = j + dj;
        if (jj < 0 || jj > 63) continue;
        as = fmaf(wi * uval(jj),
                  S[((size_t)((b << 12) + (ii << 6) + jj)) * 8 + k], as);
      }
    }
#pragma unroll
    for (int dj = -2; dj <= 2; ++dj) {
      int jj = j + dj;
      if (jj >= 0 && jj <= 63) suj += uval(jj);
    }
    as *= ui * uj;
    float sv = S[(size_t)gid * 8 + k];
    float degA = ui * uj * sui * suj;
    float numv = sv * as, denv = sv * sv * degA;
    wred2(numv, denv);
    float* lds = (float*)smem;
    int wid = tid >> 6, lane = tid & 63;
    if (lane == 0) { lds[wid * 2] = numv; lds[wid * 2 + 1] = denv; }
    __syncthreads();
    if (tid == 0) {
      int slot = b * 4 + (blk & 3);
      atomicAdd(&accg[slot], lds[0] + lds[2] + lds[4] + lds[6]);
      atomicAdd(&accg[16 + slot], lds[1] + lds[3] + lds[5] + lds[7]);
    }
  }
  if (blk < 32) {
    __syncthreads();
    int b = blk >> 3, chunk = blk & 7;
    int wid = tid >> 6, lane = tid & 63;
    int kk = lane >> 3, ll = lane & 7;
    int t0 = chunk * 512 + wid * 128;
    float a = 0.f;
    const float* Sb = S + ((size_t)b << 12) * 8;
    for (int it = 0; it < 128; ++it) {
      const float* sr = Sb + (size_t)(t0 + it) * 8;
      a = fmaf(sr[kk], sr[ll], a);
    }
    float* lds2 = (float*)smem;
    lds2[tid] = a;
    __syncthreads();
    if (tid < 64) {
      float s = lds2[tid] + lds2[tid + 64] + lds2[tid + 128] + lds2[tid + 192];
      atomicAdd(&accg[128 + b * 64 + tid], s);
    }
  }
}

// spatial smoothness per (b,k) plane
__device__ __forceinline__ void sm_stage(char* smem, int bk, int tid,
    const float* Sp, const float* w1, const float* b1, const float* g1,
    const float* bb1, const float* w2, const float* b2, const float* g2,
    const float* bb2, float* accg) {
  float* p0 = (float*)smem;
  float* p1 = p0 + 4096;
  float* red = p1 + 4096;
  int b = bk >> 3, k = bk & 7;
  const float4* src = (const float4*)(Sp + (size_t)bk * 4096);
  float4* d0 = (float4*)p0;
  for (int i2 = tid; i2 < 1024; i2 += 256) d0[i2] = src[i2];
  float W1[9], W2[9];
#pragma unroll
  for (int q = 0; q < 9; ++q) { W1[q] = w1[k * 9 + q]; W2[q] = w2[k * 9 + q]; }
  __syncthreads();
  int wid = tid >> 6, lane = tid & 63;
  float y[16];
  float s1 = 0.f, s2 = 0.f;
#pragma unroll
  for (int v = 0; v < 16; ++v) {
    int p = v * 256 + tid;
    int i2 = p >> 6, j2 = p & 63;
    float a = b1[k];
#pragma unroll
    for (int dy = 0; dy < 3; ++dy) {
      int ii = i2 + dy - 1;
      if (ii < 0 || ii > 63) continue;
#pragma unroll
      for (int dx = 0; dx < 3; ++dx) {
        int jj = j2 + dx - 1;
        if (jj < 0 || jj > 63) continue;
        a = fmaf(W1[dy * 3 + dx], p0[(ii << 6) + jj], a);
      }
    }
    y[v] = a;
    s1 += a;
    s2 = fmaf(a, a, s2);
  }
  wred2(s1, s2);
  if (lane == 0) { red[wid * 2] = s1; red[wid * 2 + 1] = s2; }
  __syncthreads();
  float mean = (red[0] + red[2] + red[4] + red[6]) * (1.f / 4096.f);
  float var = (red[1] + red[3] + red[5] + red[7]) * (1.f / 4096.f) - mean * mean;
  float inv = rsqrtf(var + 1e-5f) * g1[k];
  float sh = bb1[k];
  __syncthreads();
#pragma unroll
  for (int v = 0; v < 16; ++v) {
    int p = v * 256 + tid;
    p1[p] = fmaxf((y[v] - mean) * inv + sh, 0.f);
  }
  __syncthreads();
  s1 = 0.f; s2 = 0.f;
#pragma unroll
  for (int v = 0; v < 16; ++v) {
    int p = v * 256 + tid;
    int i2 = p >> 6, j2 = p & 63;
    float a = b2[k];
#pragma unroll
    for (int dy = 0; dy < 3; ++dy) {
      int ii = i2 + dy - 1;
      if (ii < 0 || ii > 63) continue;
#pragma unroll
      for (int dx = 0; dx < 3; ++dx) {
        int jj = j2 + dx - 1;
        if (jj < 0 || jj > 63) continue;
        a = fmaf(W2[dy * 3 + dx], p1[(ii << 6) + jj], a);
      }
    }
    y[v] = a;
    s1 += a;
    s2 = fmaf(a, a, s2);
  }
  wred2(s1, s2);
  if (lane == 0) { red[wid * 2] = s1; red[wid * 2 + 1] = s2; }
  __syncthreads();
  float mean2 = (red[0] + red[2] + red[4] + red[6]) * (1.f / 4096.f);
  float var2 = (red[1] + red[3] + red[5] + red[7]) * (1.f / 4096.f) - mean2 * mean2;
  float inv2 = rsqrtf(var2 + 1e-5f) * g2[k];
  float sh2 = bb2[k];
  float sd = 0.f;
#pragma unroll
  for (int v = 0; v < 16; ++v) {
    int p = v * 256 + tid;
    float sm = (y[v] - mean2) * inv2 + sh2;
    float dd = sm - p0[p];
    sd = fmaf(dd, dd, sd);
  }
  sd = wred(sd);
  __syncthreads();
  if (lane == 0) red[wid] = sd;
  __syncthreads();
  if (tid == 0)
    atomicAdd(&accg[384 + b * 2 + (bk & 1)],
              (red[0] + red[1] + red[2] + red[3]) * (1.f / 32768.f));
}

// edge conv via bf16 MFMA (1 row/block, A+W in LDS)
__device__ __forceinline__ void ecconv_stage(char* smem, int blk2, int tid,
    const short* fb, const short* wq, const float* ecb1, float* eraw,
    float* accg) {
  short* Abuf = (short*)smem;           // 6432 shorts
  short* Wbuf = Abuf + 6432;            // 9216 shorts
  float* sW1 = (float*)(Wbuf + 9216);   // 128
  float* sW2 = sW1 + 128;               // 128
  int b = blk2 >> 6, i = blk2 & 63;
  int wid = tid >> 6, lane = tid & 63;
  int m = lane & 15, kg = lane >> 4;
  if (tid < 36) {
    int zkg = tid & 3, sl = (tid >> 2) % 3, r = tid / 12;
    int slot = sl == 0 ? 0 : (sl == 1 ? 65 : 66);
    *(short8b*)&Abuf[(r * 67 + slot) * 32 + zkg * 8] = (short8b)0;
  }
  f32x4 acc0 = {0.f, 0.f, 0.f, 0.f};
  f32x4 acc1 = {0.f, 0.f, 0.f, 0.f};
  int abase = (wid * 16 + m) * 32 + kg * 8;
  int bbase = m * 32 + kg * 8;
  for (int c = 0; c < 12; ++c) {
    __syncthreads();
#pragma unroll
    for (int s = 0; s < 3; ++s) {
      int cid = tid + (s << 8);
      int akg = cid & 3, px = (cid >> 2) & 63, r = cid >> 8;
      int ii = i + r - 1;
      short8b v = (short8b)0;
      if (ii >= 0 && ii < 64)
        v = *(const short8b*)(fb +
              ((size_t)((b << 12) + (ii << 6) + px)) * D_ + c * 32 + akg * 8);
      *(short8b*)&Abuf[(r * 67 + px + 1) * 32 + akg * 8] = v;
    }
    for (int l = tid; l < 1152; l += 256) {
      int wkg = l & 3, oo = (l >> 2) & 31, q = l >> 7;
      short8b wv =
          *(const short8b*)(wq + ((size_t)(q * 32 + oo)) * D_ + c * 32 + wkg * 8);
      *(short8b*)&Wbuf[(q * 32 + oo) * 32 + wkg * 8] = wv;
    }
    __syncthreads();
#pragma unroll
    for (int q = 0; q < 9; ++q) {
      short8b av = *(const short8b*)&Abuf[abase + ((q / 3) * 67 + (q % 3)) * 32];
      short8b bv0 = *(const short8b*)&Wbuf[bbase + q * 1024];
      short8b bv1 = *(const short8b*)&Wbuf[bbase + q * 1024 + 512];
      acc0 = __builtin_amdgcn_mfma_f32_16x16x32_bf16(av, bv0, acc0, 0, 0, 0);
      acc1 = __builtin_amdgcn_mfma_f32_16x16x32_bf16(av, bv1, acc1, 0, 0, 0);
    }
  }
  int o0 = m, o1 = 16 + m;
  float bs0 = ecb1[o0], bs1 = ecb1[o1];
  float s1a = 0.f, s2a = 0.f, s1b = 0.f, s2b = 0.f;
  int jbase = wid * 16 + kg * 4;
#pragma unroll
  for (int rg = 0; rg < 4; ++rg) {
    float v0 = acc0[rg] + bs0;
    float v1 = acc1[rg] + bs1;
    int j = jbase + rg;
    size_t px = ((size_t)((b << 12) + (i << 6) + j)) * 32;
    eraw[px + o0] = v0;
    eraw[px + o1] = v1;
    s1a += v0; s2a = fmaf(v0, v0, s2a);
    s1b += v1; s2b = fmaf(v1, v1, s2b);
  }
  s1a += __shfl_xor(s1a, 16); s1a += __shfl_xor(s1a, 32);
  s2a += __shfl_xor(s2a, 16); s2a += __shfl_xor(s2a, 32);
  s1b += __shfl_xor(s1b, 16); s1b += __shfl_xor(s1b, 32);
  s2b += __shfl_xor(s2b, 16); s2b += __shfl_xor(s2b, 32);
  if (lane < 16) {
    sW1[wid * 32 + lane] = s1a; sW2[wid * 32 + lane] = s2a;
    sW1[wid * 32 + lane + 16] = s1b; sW2[wid * 32 + lane + 16] = s2b;
  }
  __syncthreads();
  if (tid < 32) {
    float t1 = sW1[tid] + sW1[32 + tid] + sW1[64 + tid] + sW1[96 + tid];
    float t2 = sW2[tid] + sW2[32 + tid] + sW2[64 + tid] + sW2[96 + tid];
    t1 += __shfl_xor(t1, 1); t1 += __shfl_xor(t1, 2);
    t2 += __shfl_xor(t2, 1); t2 += __shfl_xor(t2, 2);
    if ((tid & 3) == 0) {
      atomicAdd(&accg[64 + b * 16 + (tid >> 2) * 2], t1);
      atomicAdd(&accg[64 + b * 16 + (tid >> 2) * 2 + 1], t2);
    }
  }
}

__device__ __forceinline__ void ecfinal_stage(char* smem, int blk, int tid,
    const float* eraw, const float* accg, const float* gng, const float* gnb,
    const float* w2, const float* b2, float* ew) {
  float* st = (float*)smem;
  int idx = blk * 256 + tid;
  int b = idx >> 12;
  if (tid < 16) st[tid] = accg[64 + b * 16 + tid];
  __syncthreads();
  float a = b2[0];
  const float4* er = (const float4*)(eraw + (size_t)idx * 32);
#pragma unroll
  for (int oq = 0; oq < 8; ++oq) {
    float mean = st[oq * 2] * (1.f / 16384.f);
    float var = st[oq * 2 + 1] * (1.f / 16384.f) - mean * mean;
    float inv = rsqrtf(var + 1e-5f);
    float4 e = er[oq];
    int o = oq * 4;
    float v0 = (e.x - mean) * inv * gng[o + 0] + gnb[o + 0];
    float v1 = (e.y - mean) * inv * gng[o + 1] + gnb[o + 1];
    float v2 = (e.z - mean) * inv * gng[o + 2] + gnb[o + 2];
    float v3 = (e.w - mean) * inv * gng[o + 3] + gnb[o + 3];
    a = fmaf(fmaxf(v0, 0.f), w2[o + 0], a);
    a = fmaf(fmaxf(v1, 0.f), w2[o + 1], a);
    a = fmaf(fmaxf(v2, 0.f), w2[o + 2], a);
    a = fmaf(fmaxf(v3, 0.f), w2[o + 3], a);
  }
  ew[idx] = 1.f / (1.f + expf(-a));
}

// feature-smoothness gradient sums (bf16 fb); scattered atomics
__device__ __forceinline__ void fsloss_stage(char* smem, int blk, int tid,
    const short* fb, const float* ew, float* accg) {
  float sy = 0.f, sx = 0.f;
  const int N = B_ * T_ * 48;
  for (int idx = blk * 256 + tid; idx < N; idx += 512 * 256) {
    int d8 = idx % 48;
    int rt = idx / 48;
    int t = rt & (T_ - 1);
    int i = t >> 6, j = t & 63;
    const short8b* fp = (const short8b*)(fb + (size_t)rt * D_) + d8;
    short8b f0 = *fp;
    if (i < 63) {
      short8b f1 = fp[64 * 48];
      float w = ew[rt + 64];
      float a = 0.f;
#pragma unroll
      for (int u = 0; u < 8; ++u) {
        float d = bf2f(f1[u]) - bf2f(f0[u]);
        a = fmaf(d, d, a);
      }
      sy += w * a;
    }
    if (j < 63) {
      short8b f1 = fp[48];
      float w = ew[rt + 1];
      float a = 0.f;
#pragma unroll
      for (int u = 0; u < 8; ++u) {
        float d = bf2f(f1[u]) - bf2f(f0[u]);
        a = fmaf(d, d, a);
      }
      sx += w * a;
    }
  }
  wred2(sy, sx);
  float* lds = (float*)smem;
  int wid = tid >> 6, lane = tid & 63;
  if (lane == 0) { lds[wid * 2] = sy; lds[wid * 2 + 1] = sx; }
  __syncthreads();
  if (tid == 0) {
    int slot = 32 + (blk & 15) * 2;
    atomicAdd(&accg[slot], lds[0] + lds[2] + lds[4] + lds[6]);
    atomicAdd(&accg[slot + 1], lds[1] + lds[3] + lds[5] + lds[7]);
  }
}

__device__ __forceinline__ void final_stage(const float* accg, float* out) {
  float total = 0.f;
  for (int b = 0; b < 4; ++b) {
    const float* SSb = accg + 128 + b * 64;
    float ssq = 0.f;
    for (int v = 0; v < 64; ++v) ssq += SSb[v] * SSb[v];
    float ssn = sqrtf(ssq);
    float tgt = 1.f / (sqrtf(8.f) + 1e-6f);
    float inv = 1.f / (ssn + 1e-6f);
    float lo = 0.f;
    for (int kk = 0; kk < 8; ++kk)
      for (int ll = 0; ll < 8; ++ll) {
        float dd = SSb[kk * 8 + ll] * inv - (kk == ll ? tgt : 0.f);
        lo += dd * dd;
      }
    lo = sqrtf(lo);
    float num = accg[b * 4] + accg[b * 4 + 1] + accg[b * 4 + 2] + accg[b * 4 + 3];
    float den = accg[16 + b * 4] + accg[16 + b * 4 + 1] + accg[16 + b * 4 + 2] +
                accg[16 + b * 4 + 3];
    float lc = -num / (den + 1e-6f);
    float smv = accg[384 + b * 2] + accg[385 + b * 2];
    total += lc + lo + 0.01f * smv;
  }
  total *= 0.25f;
  float fsy = 0.f, fsx = 0.f;
  for (int s = 0; s < 16; ++s) { fsy += accg[32 + s * 2]; fsx += accg[33 + s * 2]; }
  const float cnt = 4.f * 384.f * 63.f * 64.f;
  float ly = fsy / cnt * (1.f / 384.f);
  float lx = fsx / cnt * (1.f / 384.f);
  out[131072] = total + 0.09f * 0.5f * (ly + lx);
}

// ============================ kernels ======================================

__global__ __launch_bounds__(256) void k_prep(PGcn p) {
  prep_stage(blockIdx.x, threadIdx.x, p.feat, p.ecw1, p.w0, p.resw, p.fb, p.wq,
             p.wb, p.accg);
}

// ecconv (blk<256) || gemm0 (blk>=256, 512 blocks)
__global__ __launch_bounds__(256) void k_mix1(PGcn g, PLoss l) {
  __shared__ __align__(16) char smem[57344];
  if (blockIdx.x < 256)
    ecconv_stage(smem, blockIdx.x, threadIdx.x, l.fb, l.wq, l.ecb1, l.eraw,
                 l.accg);
  else
    gemm0_stage(smem, blockIdx.x - 256, threadIdx.x, g.fb, g.wb, g.w0, g.resw,
                g.resb, g.resg, g.reslb, g.xwA, g.resbuf);
}

// ecfinal (blk<64) || layer0 (blk>=64, 1024 blocks)
__global__ __launch_bounds__(256) void k_mix2(PGcn g, PLoss l) {
  __shared__ __align__(16) char smem[20480];
  if (blockIdx.x < 64)
    ecfinal_stage(smem, blockIdx.x, threadIdx.x, l.eraw, l.accg, l.gng, l.gnb,
                  l.ecw2, l.ecb2, l.ew);
  else
    layer_stage(smem, blockIdx.x - 64, threadIdx.x, g.xwA, g.gw, g.gb0, g.lng,
                g.lnb, g.resbuf, g.xbuf, g.xwB);
}

// fsloss (blk<512) || layer1 (blk>=512, 1024 blocks)
__global__ __launch_bounds__(256) void k_mix3(PGcn g, PLoss l) {
  __shared__ __align__(16) char smem[20480];
  if (blockIdx.x < 512)
    fsloss_stage(smem, blockIdx.x, threadIdx.x, l.fb, l.ew, l.accg);
  else
    layer_stage(smem, blockIdx.x - 512, threadIdx.x, g.xwB, g.gw + 4096, g.gb,
                g.lng + 64, g.lnb + 64, g.xbuf, g.xbuf, g.xwA);
}

__global__ __launch_bounds__(256) void k_layer2(PGcn p) {
  __shared__ __align__(16) char smem[20480];
  layer_stage(smem, blockIdx.x, threadIdx.x, p.xwA, p.gw + 8192, p.gb + 64,
              p.lng + 128, p.lnb + 128, p.xbuf, p.xbuf, p.xwB);
}

__global__ __launch_bounds__(256) void k_st4mlp(PGcn p) {
  __shared__ __align__(16) char smem[32768];
  st4mlp_stage(smem, blockIdx.x, threadIdx.x, p.xwB, p.gb + 128, p.lng + 192,
               p.lnb + 192, p.xbuf, p.w1, p.b1, p.mlng, p.mlnb, p.w2, p.b2,
               p.S, p.Sp);
}

// cut (blk<512) || sm (blk>=512, 32 blocks)
__global__ __launch_bounds__(256) void k_cutsm(PLoss p) {
  __shared__ __align__(16) char smem[32832];
  if (blockIdx.x < 512)
    cut_stage(smem, blockIdx.x, threadIdx.x, p.S, p.accg);
  else
    sm_stage(smem, blockIdx.x - 512, threadIdx.x, p.Sp, p.smw1, p.smb1, p.smg1,
             p.smbb1, p.smw2, p.smb2, p.smg2, p.smbb2, p.accg);
}

__global__ void k_final(PLoss p) {
  if (threadIdx.x == 0 && blockIdx.x == 0) final_stage(p.accg, p.outp);
}

// ================================ host =====================================

extern "C" void kernel_launch(void* const* d_in, const int* in_sizes, int n_in,
                              void* d_out, int out_size, void* d_ws, size_t ws_size,
                              hipStream_t stream) {
  const float* feat = (const float*)d_in[0];
  const float* gcn_w0 = (const float*)d_in[1];
  const float* gcn_b0 = (const float*)d_in[2];
  const float* gcn_w = (const float*)d_in[3];
  const float* gcn_b = (const float*)d_in[4];
  const float* ln_g = (const float*)d_in[5];
  const float* ln_b = (const float*)d_in[6];
  const float* res_w = (const float*)d_in[7];
  const float* res_b = (const float*)d_in[8];
  const float* res_ln_g = (const float*)d_in[9];
  const float* res_ln_b = (const float*)d_in[10];
  const float* mlp_w1 = (const float*)d_in[11];
  const float* mlp_b1 = (const float*)d_in[12];
  const float* mlp_ln_g = (const float*)d_in[13];
  const float* mlp_ln_b = (const float*)d_in[14];
  const float* mlp_w2 = (const float*)d_in[15];
  const float* mlp_b2 = (const float*)d_in[16];
  const float* sm_w1 = (const float*)d_in[17];
  const float* sm_b1 = (const float*)d_in[18];
  const float* sm_g1 = (const float*)d_in[19];
  const float* sm_bb1 = (const float*)d_in[20];
  const float* sm_w2 = (const float*)d_in[21];
  const float* sm_b2 = (const float*)d_in[22];
  const float* sm_g2 = (const float*)d_in[23];
  const float* sm_bb2 = (const float*)d_in[24];
  const float* ec_w1 = (const float*)d_in[25];
  const float* ec_b1 = (const float*)d_in[26];
  const float* ec_gn_g = (const float*)d_in[27];
  const float* ec_gn_b = (const float*)d_in[28];
  const float* ec_w2 = (const float*)d_in[29];
  const float* ec_b2 = (const float*)d_in[30];

  float* out = (float*)d_out;
  float* ws = (float*)d_ws;
  float* acc = ws;                       // 512 floats
  float* xwA = ws + 512;
  float* xwB = xwA + 1048576;
  float* xbuf = xwB + 1048576;
  float* resbuf = xbuf + 1048576;
  float* Sp = resbuf + 1048576;          // B*K*T
  float* eraw = Sp + 131072;             // B*T*32 pixel-major
  float* ew = eraw + 524288;             // B*T
  short* wqb = (short*)(ew + 16384);     // 110592 bf16
  short* wb = wqb + 110592;              // 49152 bf16 frag order
  short* fb = wb + 49152;                // B*T*384 bf16 (prep)
  float* S = out;

  PGcn pg = {feat, ec_w1, gcn_w0, res_w, res_b, res_ln_g, res_ln_b,
             gcn_w, gcn_b0, gcn_b, ln_g, ln_b,
             mlp_w1, mlp_b1, mlp_ln_g, mlp_ln_b, mlp_w2, mlp_b2,
             fb, wqb, wb, acc, xwA, xwB, xbuf, resbuf, S, Sp};
  PLoss pl = {S, Sp, sm_w1, sm_b1, sm_g1, sm_bb1, sm_w2, sm_b2, sm_g2, sm_bb2,
              fb, wqb, ec_b1, eraw, acc, ec_gn_g, ec_gn_b, ec_w2, ec_b2, ew,
              out};

  k_prep<<<3528, 256, 0, stream>>>(pg);
  k_mix1<<<768, 256, 0, stream>>>(pg, pl);    // ecconv || gemm0
  k_mix2<<<1088, 256, 0, stream>>>(pg, pl);   // ecfinal || layer0
  k_mix3<<<1536, 256, 0, stream>>>(pg, pl);   // fsloss || layer1
  k_layer2<<<1024, 256, 0, stream>>>(pg);
  k_st4mlp<<<512, 256, 0, stream>>>(pg);
  k_cutsm<<<544, 256, 0, stream>>>(pl);       // cut || sm
  k_final<<<1, 64, 0, stream>>>(pl);
}